// Round 9
// baseline (308.951 us; speedup 1.0000x reference)
//
#include <hip/hip_runtime.h>
#include <math.h>

// Problem constants (fixed by the reference)
#define B_SZ    2
#define LSEQ    1024
#define DIM     1024
#define DSTATE  16
#define DCONV   4
#define DIN     2048          // d_inner
#define MROWS   (B_SZ * LSEQ) // 2048
#define CH      (B_SZ * DIN)  // 4096 channels
#define NCHUNK  32
#define LC      (LSEQ / NCHUNK)  // 32
#define BCROWS  8             // rows per bc_proj block

typedef short  bf16x8 __attribute__((ext_vector_type(8)));
typedef float  f32x4  __attribute__((ext_vector_type(4)));

__device__ __forceinline__ float softplus_f(float x) {
    return fmaxf(x, 0.0f) + log1pf(__expf(-fabsf(x)));
}

__device__ __forceinline__ unsigned short f2bf(float x) {
    unsigned u = __float_as_uint(x);
    u = (u + 0x7FFF + ((u >> 16) & 1)) >> 16;
    return (unsigned short)u;
}

__device__ __forceinline__ float bf2f(unsigned short u) {
    return __uint_as_float((unsigned)u << 16);
}

__device__ __forceinline__ void load_lds16(const void* g, void* l) {
    __builtin_amdgcn_global_load_lds(
        (const __attribute__((address_space(1))) unsigned int*)g,
        (__attribute__((address_space(3))) unsigned int*)l, 16, 0, 0);
}

// ---------------------------------------------------------------------------
// f32 -> bf16 conversion (vectorized, 4 elems/thread)
// ---------------------------------------------------------------------------
__global__ __launch_bounds__(256) void f32_to_bf16(
    const float* __restrict__ src, unsigned short* __restrict__ dst, int n)
{
    int i = (blockIdx.x * 256 + threadIdx.x) * 4;
    if (i >= n) return;
    const float4 v = *reinterpret_cast<const float4*>(src + i);
    ushort4 o;
    o.x = f2bf(v.x); o.y = f2bf(v.y); o.z = f2bf(v.z); o.w = f2bf(v.w);
    *reinterpret_cast<ushort4*>(dst + i) = o;
}

// ---------------------------------------------------------------------------
// delta = softplus(P0 + P1 + b_dt[col]); P1 split across two regions by row.
// ---------------------------------------------------------------------------
__global__ __launch_bounds__(256) void finalize_delta(
    float* __restrict__ delta, const float* __restrict__ P1lo,
    const float* __restrict__ P1hi, const float* __restrict__ b_dt)
{
    int i = (blockIdx.x * 256 + threadIdx.x) * 4;
    int r = i >> 11;
    const float* p1 = (r < 1024) ? P1lo : P1hi;
    float4 v = *reinterpret_cast<float4*>(delta + i);
    const float4 u = *reinterpret_cast<const float4*>(p1 + i);
    const float4 b = *reinterpret_cast<const float4*>(b_dt + (i & (DIN - 1)));
    v.x = softplus_f(v.x + u.x + b.x);
    v.y = softplus_f(v.y + u.y + b.y);
    v.z = softplus_f(v.z + u.z + b.z);
    v.w = softplus_f(v.w + u.w + b.w);
    *reinterpret_cast<float4*>(delta + i) = v;
}

// out = x + Q0 + Q1 + Q2 + Q3   [MROWS*DIM]
__global__ __launch_bounds__(256) void out_combine(
    const float* __restrict__ x, const float* __restrict__ Q0,
    const float* __restrict__ Q1, const float* __restrict__ Q2,
    const float* __restrict__ Q3, float* __restrict__ out)
{
    int i = (blockIdx.x * 256 + threadIdx.x) * 4;
    const float4 a = *reinterpret_cast<const float4*>(x + i);
    const float4 q0 = *reinterpret_cast<const float4*>(Q0 + i);
    const float4 q1 = *reinterpret_cast<const float4*>(Q1 + i);
    const float4 q2 = *reinterpret_cast<const float4*>(Q2 + i);
    const float4 q3 = *reinterpret_cast<const float4*>(Q3 + i);
    float4 o;
    o.x = a.x + ((q0.x + q1.x) + (q2.x + q3.x));
    o.y = a.y + ((q0.y + q1.y) + (q2.y + q3.y));
    o.z = a.z + ((q0.z + q1.z) + (q2.z + q3.z));
    o.w = a.w + ((q0.w + q1.w) + (q2.w + q3.w));
    *reinterpret_cast<float4*>(out + i) = o;
}

// ---------------------------------------------------------------------------
// bf16 MFMA NT GEMM (unchanged from r8): 128x128 tile, BK=64, dbuf LDS 64 KB,
// k-slot-major conflict-free layout, plain-store split-K partials.
// ---------------------------------------------------------------------------
template <int MODE>
__global__ __launch_bounds__(256) void gemm_bf16(
    const unsigned short* __restrict__ A, const unsigned short* __restrict__ Bm,
    int M, int N, int K, int Ksub,
    float* __restrict__ C0, float* __restrict__ C1,
    float* __restrict__ C2, float* __restrict__ C3)
{
    __shared__ unsigned short As[2][128 * 64];   // 2 x 16 KB
    __shared__ unsigned short Bs[2][128 * 64];   // 2 x 16 KB

    const int t    = threadIdx.x;
    const int lane = t & 63;
    const int w    = t >> 6;
    const int wr   = w >> 1;
    const int wc   = w & 1;
    const int row0 = blockIdx.y * 128;
    const int col0 = blockIdx.x * 128;
    const int z     = blockIdx.z;
    const int kbase = z * Ksub;

    const int lrow  = lane & 15;
    const int kslot = lane >> 4;

    float* C = C0;
    if (MODE == 1 && z == 1) C = (row0 < 1024) ? C1 : C2;
    if (MODE == 2) C = (z == 0) ? C0 : (z == 1) ? C1 : (z == 2) ? C2 : C3;

    f32x4 acc[4][4];
    #pragma unroll
    for (int i = 0; i < 4; ++i)
        #pragma unroll
        for (int j = 0; j < 4; ++j)
            acc[i][j] = (f32x4){0.f, 0.f, 0.f, 0.f};

    const int wbase = w << 10;

    auto stage = [&](int k0, int buf) {
        #pragma unroll
        for (int p = 0; p < 4; ++p) {
            const int u   = t + p * 256;
            const int ks8 = u >> 7;
            const int row = u & 127;
            load_lds16(A  + (size_t)(row0 + row) * K + k0 + ks8 * 8,
                       (char*)&As[buf][0] + p * 4096 + wbase);
            load_lds16(Bm + (size_t)(col0 + row) * K + k0 + ks8 * 8,
                       (char*)&Bs[buf][0] + p * 4096 + wbase);
        }
    };

    const int NT = Ksub >> 6;
    stage(kbase, 0);
    __syncthreads();

    int cur = 0;
    for (int kt = 0; kt < NT; ++kt) {
        if (kt + 1 < NT) stage(kbase + ((kt + 1) << 6), cur ^ 1);

        #pragma unroll
        for (int s = 0; s < 2; ++s) {
            bf16x8 af[4], bf[4];
            #pragma unroll
            for (int i = 0; i < 4; ++i)
                af[i] = *reinterpret_cast<const bf16x8*>(
                    &As[cur][(s * 4 + kslot) * (128 * 8) + (wr * 64 + i * 16 + lrow) * 8]);
            #pragma unroll
            for (int j = 0; j < 4; ++j)
                bf[j] = *reinterpret_cast<const bf16x8*>(
                    &Bs[cur][(s * 4 + kslot) * (128 * 8) + (wc * 64 + j * 16 + lrow) * 8]);
            #pragma unroll
            for (int i = 0; i < 4; ++i)
                #pragma unroll
                for (int j = 0; j < 4; ++j)
                    acc[i][j] = __builtin_amdgcn_mfma_f32_16x16x32_bf16(af[i], bf[j], acc[i][j], 0, 0, 0);
        }
        __syncthreads();
        cur ^= 1;
    }

    #pragma unroll
    for (int i = 0; i < 4; ++i) {
        const int r0 = row0 + wr * 64 + i * 16 + (lane >> 4) * 4;
        #pragma unroll
        for (int j = 0; j < 4; ++j) {
            const int c = col0 + wc * 64 + j * 16 + lrow;
            #pragma unroll
            for (int q = 0; q < 4; ++q) {
                const int r = r0 + q;
                C[(size_t)r * N + c] = acc[i][j][q];
            }
        }
    }
}

// ---------------------------------------------------------------------------
// Causal depthwise conv(4) + bias + SiLU -> bf16 xcb.
// ---------------------------------------------------------------------------
__global__ __launch_bounds__(256) void conv_silu(
    const float* __restrict__ xz, const float* __restrict__ Wc,
    const float* __restrict__ bc, unsigned short* __restrict__ xcb)
{
    int idx = blockIdx.x * 256 + threadIdx.x;      // m*DIN + e
    int e = idx & (DIN - 1);
    int m = idx >> 11;
    int l = m & (LSEQ - 1);

    const float4 w = reinterpret_cast<const float4*>(Wc)[e];
    float acc = bc[e];
    if (l >= 3) acc = fmaf(xz[(size_t)(m - 3) * (2 * DIN) + e], w.x, acc);
    if (l >= 2) acc = fmaf(xz[(size_t)(m - 2) * (2 * DIN) + e], w.y, acc);
    if (l >= 1) acc = fmaf(xz[(size_t)(m - 1) * (2 * DIN) + e], w.z, acc);
    acc = fmaf(xz[(size_t)m * (2 * DIN) + e], w.w, acc);
    float s = acc / (1.0f + __expf(-acc));
    xcb[idx] = f2bf(s);
}

// ---------------------------------------------------------------------------
// Build Wt[j][o] = (o<16 ? W_B : W_C)[o&15][j]   -> [DIN][32] f32 (256 KB)
// One-time transform so bc_proj's weight loads are coalesced across o-lanes.
// ---------------------------------------------------------------------------
__global__ __launch_bounds__(256) void wt_build(
    const float* __restrict__ WB, const float* __restrict__ WC,
    float* __restrict__ Wt)
{
    int idx = blockIdx.x * 256 + threadIdx.x;   // j*32 + o
    int j = idx >> 5;
    int o = idx & 31;
    Wt[idx] = (o < 16) ? WB[(size_t)o * DIN + j] : WC[(size_t)(o - 16) * DIN + j];
}

// ---------------------------------------------------------------------------
// B_t / C_t projections v2: 256 blocks x 8 rows.
// Rows staged to LDS f32 (64 KB) via coalesced 16B bf16 loads.
// Thread (r=t>>5, o=t&31): dot(rows[r], Wt[:,o]) — Wt load is 128B coalesced
// across the 32 o-lanes; rows[r][j] is a 2-way LDS broadcast (free).
// ---------------------------------------------------------------------------
__global__ __launch_bounds__(256) void bc_proj(
    const unsigned short* __restrict__ xcb, const float* __restrict__ Wt,
    float* __restrict__ Bt, float* __restrict__ Ct)
{
    __shared__ float rows[BCROWS][DIN];          // 64 KB
    const int m0 = blockIdx.x * BCROWS;

    // stage 8 rows: 2048 chunks of 8 bf16 (16B); 256 threads x 8 iters
    for (int u = threadIdx.x; u < (BCROWS * DIN) / 8; u += 256) {
        const int r  = u >> 8;                   // DIN/8 = 256 chunks/row
        const int jc = u & 255;
        const uint4 v = *reinterpret_cast<const uint4*>(
            &xcb[(size_t)(m0 + r) * DIN + jc * 8]);
        float* dst = &rows[r][jc * 8];
        dst[0] = bf2f((unsigned short)(v.x & 0xffff));
        dst[1] = bf2f((unsigned short)(v.x >> 16));
        dst[2] = bf2f((unsigned short)(v.y & 0xffff));
        dst[3] = bf2f((unsigned short)(v.y >> 16));
        dst[4] = bf2f((unsigned short)(v.z & 0xffff));
        dst[5] = bf2f((unsigned short)(v.z >> 16));
        dst[6] = bf2f((unsigned short)(v.w & 0xffff));
        dst[7] = bf2f((unsigned short)(v.w >> 16));
    }
    __syncthreads();

    const int r = threadIdx.x >> 5;              // 0..7
    const int o = threadIdx.x & 31;              // 0..31
    float p = 0.0f;
    #pragma unroll 8
    for (int j = 0; j < DIN; ++j)
        p = fmaf(rows[r][j], Wt[(size_t)j * 32 + o], p);

    const int m = m0 + r;
    if (o < DSTATE) Bt[(size_t)m * DSTATE + o] = p;
    else            Ct[(size_t)m * DSTATE + (o - DSTATE)] = p;
}

// ---------------------------------------------------------------------------
// Chunked selective scan — pass 1: per-chunk local scan from h=0.
// ---------------------------------------------------------------------------
__global__ __launch_bounds__(256) void scan_pass1(
    const float* __restrict__ delta, const unsigned short* __restrict__ xcb,
    const float* __restrict__ Bt, const float* __restrict__ A_log,
    float* __restrict__ hfin, float* __restrict__ dsums)
{
    const int ge = blockIdx.x * 256 + threadIdx.x;
    const int c  = blockIdx.y;
    const int b  = ge >> 11;
    const int e  = ge & (DIN - 1);

    float A[DSTATE];
    #pragma unroll
    for (int s = 0; s < DSTATE; ++s) A[s] = -__expf(A_log[s]);

    float h[DSTATE] = {};
    float dsum = 0.0f;
    const int m0 = b * LSEQ + c * LC;

    for (int l = 0; l < LC; ++l) {
        const int m = m0 + l;
        const float dv = delta[(size_t)m * DIN + e];
        const float xv = bf2f(xcb[(size_t)m * DIN + e]);
        dsum += dv;
        const float dx = dv * xv;
        #pragma unroll
        for (int s = 0; s < DSTATE; ++s) {
            const float bv = Bt[(size_t)m * DSTATE + s];
            h[s] = fmaf(h[s], __expf(dv * A[s]), dx * bv);
        }
    }

    float4* hf = reinterpret_cast<float4*>(&hfin[((size_t)ge * NCHUNK + c) * DSTATE]);
    #pragma unroll
    for (int q = 0; q < 4; ++q)
        hf[q] = make_float4(h[4*q], h[4*q+1], h[4*q+2], h[4*q+3]);
    dsums[(size_t)ge * NCHUNK + c] = dsum;
}

// ---------------------------------------------------------------------------
// Pass 2: sequential combine over chunks (in place).
// ---------------------------------------------------------------------------
__global__ __launch_bounds__(256) void scan_pass2(
    float* __restrict__ hfin, const float* __restrict__ dsums,
    const float* __restrict__ A_log)
{
    const int t  = blockIdx.x * 256 + threadIdx.x;
    const int ge = t >> 4;
    const int s  = t & 15;
    const float A = -__expf(A_log[s]);

    float h = 0.0f;
    for (int c = 0; c < NCHUNK; ++c) {
        const size_t idx = ((size_t)ge * NCHUNK + c) * DSTATE + s;
        const float hf = hfin[idx];
        hfin[idx] = h;
        const float P = __expf(A * dsums[(size_t)ge * NCHUNK + c]);
        h = fmaf(P, h, hf);
    }
}

// ---------------------------------------------------------------------------
// Pass 3: re-run local scan with carry-in; fuse C-dot, D, silu(z); bf16 out.
// ---------------------------------------------------------------------------
__global__ __launch_bounds__(256) void scan_pass3(
    const float* __restrict__ delta, const unsigned short* __restrict__ xcb,
    const float* __restrict__ Bt, const float* __restrict__ Ct,
    const float* __restrict__ xz, const float* __restrict__ A_log,
    const float* __restrict__ Dv, const float* __restrict__ hcar,
    unsigned short* __restrict__ ygb)
{
    const int ge = blockIdx.x * 256 + threadIdx.x;
    const int c  = blockIdx.y;
    const int b  = ge >> 11;
    const int e  = ge & (DIN - 1);

    float A[DSTATE];
    #pragma unroll
    for (int s = 0; s < DSTATE; ++s) A[s] = -__expf(A_log[s]);

    float h[DSTATE];
    const float4* hc = reinterpret_cast<const float4*>(&hcar[((size_t)ge * NCHUNK + c) * DSTATE]);
    #pragma unroll
    for (int q = 0; q < 4; ++q) {
        const float4 v = hc[q];
        h[4*q]   = v.x; h[4*q+1] = v.y; h[4*q+2] = v.z; h[4*q+3] = v.w;
    }

    const float Dval = Dv[e];
    const int m0 = b * LSEQ + c * LC;

    for (int l = 0; l < LC; ++l) {
        const int m = m0 + l;
        const float dv = delta[(size_t)m * DIN + e];
        const float xv = bf2f(xcb[(size_t)m * DIN + e]);
        const float dx = dv * xv;
        float y = xv * Dval;
        #pragma unroll
        for (int s = 0; s < DSTATE; ++s) {
            const float bv = Bt[(size_t)m * DSTATE + s];
            const float cv = Ct[(size_t)m * DSTATE + s];
            h[s] = fmaf(h[s], __expf(dv * A[s]), dx * bv);
            y = fmaf(h[s], cv, y);
        }
        const float zv = xz[(size_t)m * (2 * DIN) + DIN + e];
        const float sz = zv / (1.0f + __expf(-zv));
        ygb[(size_t)m * DIN + e] = f2bf(y * sz);
    }
}

// ---------------------------------------------------------------------------
extern "C" void kernel_launch(void* const* d_in, const int* in_sizes, int n_in,
                              void* d_out, int out_size, void* d_ws, size_t ws_size,
                              hipStream_t stream)
{
    const float* x      = (const float*)d_in[0];
    const float* W_in   = (const float*)d_in[1];
    const float* W_conv = (const float*)d_in[2];
    const float* b_conv = (const float*)d_in[3];
    const float* W_dt   = (const float*)d_in[4];
    const float* b_dt   = (const float*)d_in[5];
    const float* W_B    = (const float*)d_in[6];
    const float* W_C    = (const float*)d_in[7];
    const float* A_log  = (const float*)d_in[8];
    const float* Dvec   = (const float*)d_in[9];
    const float* W_out  = (const float*)d_in[10];
    float* out = (float*)d_out;

    // Workspace layout (84.75 MB total, same as r4-r8):
    float* ws    = (float*)d_ws;
    float* xz    = ws;                                  // [2048,4096] f32  32 MB
    float* delta = xz + (size_t)MROWS * 2 * DIN;        // [2048,2048] f32  16 MB
    float* Bt    = delta + (size_t)MROWS * DIN;         // [2048,16]   f32
    float* Ct    = Bt + (size_t)MROWS * DSTATE;         // [2048,16]   f32
    float* hfin  = Ct + (size_t)MROWS * DSTATE;         // [4096,32,16] f32  8 MB
    float* dsums = hfin + (size_t)CH * NCHUNK * DSTATE; // [4096,32]   f32  0.5 MB
    unsigned short* xb   = (unsigned short*)(dsums + (size_t)CH * NCHUNK); // [2048,1024] bf16 4 MB
    unsigned short* wbuf = xb + (size_t)MROWS * DIM;        // up to 4M bf16   8 MB
    unsigned short* xcb  = wbuf + (size_t)4 * 1024 * 1024;  // [2048,2048] bf16 8 MB
    unsigned short* ygb  = xcb + (size_t)MROWS * DIN;       // [2048,2048] bf16 8 MB

    // region-reuse views (fp32) for split-K partials
    float* hfinF  = hfin;                                   // 8 MB: G2 P1 rows<1024; later G3 Q2
    float* ygbF   = (float*)ygb;                            // 8 MB: G2 P1 rows>=1024 (pre-offset)
    float* xcbF   = (float*)xcb;                            // 8 MB: G3 Q3
    float* Wt     = dsums;                                  // 256 KB: bc_proj weights (dead until scan_pass1)
    const size_t SZ3 = (size_t)MROWS * DIM;                 // 2M floats = 8 MB

    // 1. xz = x @ W_in^T   [2048,4096], K=1024 -> 512 blocks (2/CU), plain
    f32_to_bf16<<<(MROWS * DIM) / 1024, 256, 0, stream>>>(x, xb, MROWS * DIM);
    f32_to_bf16<<<(2 * DIN * DIM) / 1024, 256, 0, stream>>>(W_in, wbuf, 2 * DIN * DIM);
    gemm_bf16<0><<<dim3((2 * DIN) / 128, MROWS / 128, 1), 256, 0, stream>>>(
        xb, wbuf, MROWS, 2 * DIN, DIM, DIM, xz, nullptr, nullptr, nullptr);

    // 2. causal conv + silu -> xcb (bf16)
    conv_silu<<<(MROWS * DIN) / 256, 256, 0, stream>>>(xz, W_conv, b_conv, xcb);

    // 3. delta partials: z=2 split (512 blocks, 2/CU), plain stores.
    f32_to_bf16<<<(DIN * DIN) / 1024, 256, 0, stream>>>(W_dt, wbuf, DIN * DIN);
    gemm_bf16<1><<<dim3(DIN / 128, MROWS / 128, 2), 256, 0, stream>>>(
        xcb, wbuf, MROWS, DIN, DIN, DIN / 2,
        delta, hfinF, ygbF - (size_t)1024 * DIN, nullptr);
    finalize_delta<<<(MROWS * DIN) / 1024, 256, 0, stream>>>(
        delta, hfinF, ygbF - (size_t)1024 * DIN, b_dt);

    // 4. B_t, C_t projections (coalesced Wt + LDS-staged rows)
    wt_build<<<(DIN * 32) / 256, 256, 0, stream>>>(W_B, W_C, Wt);
    bc_proj<<<MROWS / BCROWS, 256, 0, stream>>>(xcb, Wt, Bt, Ct);

    // 5. chunked selective scan -> ygb (bf16)
    scan_pass1<<<dim3(CH / 256, NCHUNK), 256, 0, stream>>>(
        delta, xcb, Bt, A_log, hfin, dsums);
    scan_pass2<<<(CH * DSTATE) / 256, 256, 0, stream>>>(hfin, dsums, A_log);
    scan_pass3<<<dim3(CH / 256, NCHUNK), 256, 0, stream>>>(
        delta, xcb, Bt, Ct, xz, A_log, Dvec, hfin, ygb);

    // 6. out partials: z=4 split (512 blocks, 2/CU), plain stores into
    //    dead regions: Q0,Q1 = delta region; Q2 = hfin; Q3 = xcb region.
    f32_to_bf16<<<(DIM * DIN) / 1024, 256, 0, stream>>>(W_out, wbuf, DIM * DIN);
    gemm_bf16<2><<<dim3(DIM / 128, MROWS / 128, 4), 256, 0, stream>>>(
        ygb, wbuf, MROWS, DIM, DIN, DIN / 4,
        delta, delta + SZ3, hfinF, xcbF);
    out_combine<<<(MROWS * DIM) / 1024, 256, 0, stream>>>(
        x, delta, delta + SZ3, hfinF, xcbF, out);
}

// Round 10
// 285.326 us; speedup vs baseline: 1.0828x; 1.0828x over previous
//
#include <hip/hip_runtime.h>
#include <math.h>

// Problem constants (fixed by the reference)
#define B_SZ    2
#define LSEQ    1024
#define DIM     1024
#define DSTATE  16
#define DCONV   4
#define DIN     2048          // d_inner
#define MROWS   (B_SZ * LSEQ) // 2048
#define CH      (B_SZ * DIN)  // 4096 channels
#define NCHUNK  32
#define LC      (LSEQ / NCHUNK)  // 32

typedef short  bf16x8 __attribute__((ext_vector_type(8)));
typedef float  f32x4  __attribute__((ext_vector_type(4)));

__device__ __forceinline__ float softplus_f(float x) {
    return fmaxf(x, 0.0f) + log1pf(__expf(-fabsf(x)));
}

__device__ __forceinline__ unsigned short f2bf(float x) {
    unsigned u = __float_as_uint(x);
    u = (u + 0x7FFF + ((u >> 16) & 1)) >> 16;
    return (unsigned short)u;
}

__device__ __forceinline__ float bf2f(unsigned short u) {
    return __uint_as_float((unsigned)u << 16);
}

__device__ __forceinline__ void load_lds16(const void* g, void* l) {
    __builtin_amdgcn_global_load_lds(
        (const __attribute__((address_space(1))) unsigned int*)g,
        (__attribute__((address_space(3))) unsigned int*)l, 16, 0, 0);
}

// ---------------------------------------------------------------------------
// f32 -> bf16 conversion (vectorized, 4 elems/thread)
// ---------------------------------------------------------------------------
__global__ __launch_bounds__(256) void f32_to_bf16(
    const float* __restrict__ src, unsigned short* __restrict__ dst, int n)
{
    int i = (blockIdx.x * 256 + threadIdx.x) * 4;
    if (i >= n) return;
    const float4 v = *reinterpret_cast<const float4*>(src + i);
    ushort4 o;
    o.x = f2bf(v.x); o.y = f2bf(v.y); o.z = f2bf(v.z); o.w = f2bf(v.w);
    *reinterpret_cast<ushort4*>(dst + i) = o;
}

// ---------------------------------------------------------------------------
// Pack [W_B; W_C; zero-pad] -> Wbc [128][DIN] bf16 for the skinny MFMA GEMM.
// ---------------------------------------------------------------------------
__global__ __launch_bounds__(256) void wbc_build(
    const float* __restrict__ WB, const float* __restrict__ WC,
    unsigned short* __restrict__ Wbc)
{
    int idx = blockIdx.x * 256 + threadIdx.x;   // row*DIN + j, row in [0,128)
    int row = idx >> 11;
    int j   = idx & (DIN - 1);
    float v = 0.0f;
    if (row < DSTATE)           v = WB[(size_t)row * DIN + j];
    else if (row < 2 * DSTATE)  v = WC[(size_t)(row - DSTATE) * DIN + j];
    Wbc[idx] = f2bf(v);
}

// ---------------------------------------------------------------------------
// delta = softplus(P0 + P1 + b_dt[col]); P1 split across two regions by row.
// ---------------------------------------------------------------------------
__global__ __launch_bounds__(256) void finalize_delta(
    float* __restrict__ delta, const float* __restrict__ P1lo,
    const float* __restrict__ P1hi, const float* __restrict__ b_dt)
{
    int i = (blockIdx.x * 256 + threadIdx.x) * 4;
    int r = i >> 11;
    const float* p1 = (r < 1024) ? P1lo : P1hi;
    float4 v = *reinterpret_cast<float4*>(delta + i);
    const float4 u = *reinterpret_cast<const float4*>(p1 + i);
    const float4 b = *reinterpret_cast<const float4*>(b_dt + (i & (DIN - 1)));
    v.x = softplus_f(v.x + u.x + b.x);
    v.y = softplus_f(v.y + u.y + b.y);
    v.z = softplus_f(v.z + u.z + b.z);
    v.w = softplus_f(v.w + u.w + b.w);
    *reinterpret_cast<float4*>(delta + i) = v;
}

// out = x + Q0 + Q1 + Q2 + Q3   [MROWS*DIM]
__global__ __launch_bounds__(256) void out_combine(
    const float* __restrict__ x, const float* __restrict__ Q0,
    const float* __restrict__ Q1, const float* __restrict__ Q2,
    const float* __restrict__ Q3, float* __restrict__ out)
{
    int i = (blockIdx.x * 256 + threadIdx.x) * 4;
    const float4 a = *reinterpret_cast<const float4*>(x + i);
    const float4 q0 = *reinterpret_cast<const float4*>(Q0 + i);
    const float4 q1 = *reinterpret_cast<const float4*>(Q1 + i);
    const float4 q2 = *reinterpret_cast<const float4*>(Q2 + i);
    const float4 q3 = *reinterpret_cast<const float4*>(Q3 + i);
    float4 o;
    o.x = a.x + ((q0.x + q1.x) + (q2.x + q3.x));
    o.y = a.y + ((q0.y + q1.y) + (q2.y + q3.y));
    o.z = a.z + ((q0.z + q1.z) + (q2.z + q3.z));
    o.w = a.w + ((q0.w + q1.w) + (q2.w + q3.w));
    *reinterpret_cast<float4*>(out + i) = o;
}

// ---------------------------------------------------------------------------
// bf16 MFMA NT GEMM (r8 core): 128x128 tile, BK=64, dbuf LDS 64 KB,
// k-slot-major conflict-free layout, plain-store split-K partials.
//   MODE 0: C0[r*N+c]                       (single slice)
//   MODE 1: z0->C0; z1-> (row<1024 ? C1 : C2)[r*N+c]   (C2 pre-offset)
//   MODE 2: {C0,C1,C2,C3}[z][r*N+c]
// ---------------------------------------------------------------------------
template <int MODE>
__global__ __launch_bounds__(256) void gemm_bf16(
    const unsigned short* __restrict__ A, const unsigned short* __restrict__ Bm,
    int M, int N, int K, int Ksub,
    float* __restrict__ C0, float* __restrict__ C1,
    float* __restrict__ C2, float* __restrict__ C3)
{
    __shared__ unsigned short As[2][128 * 64];   // 2 x 16 KB
    __shared__ unsigned short Bs[2][128 * 64];   // 2 x 16 KB

    const int t    = threadIdx.x;
    const int lane = t & 63;
    const int w    = t >> 6;
    const int wr   = w >> 1;
    const int wc   = w & 1;
    const int row0 = blockIdx.y * 128;
    const int col0 = blockIdx.x * 128;
    const int z     = blockIdx.z;
    const int kbase = z * Ksub;

    const int lrow  = lane & 15;
    const int kslot = lane >> 4;

    float* C = C0;
    if (MODE == 1 && z == 1) C = (row0 < 1024) ? C1 : C2;
    if (MODE == 2) C = (z == 0) ? C0 : (z == 1) ? C1 : (z == 2) ? C2 : C3;

    f32x4 acc[4][4];
    #pragma unroll
    for (int i = 0; i < 4; ++i)
        #pragma unroll
        for (int j = 0; j < 4; ++j)
            acc[i][j] = (f32x4){0.f, 0.f, 0.f, 0.f};

    const int wbase = w << 10;

    auto stage = [&](int k0, int buf) {
        #pragma unroll
        for (int p = 0; p < 4; ++p) {
            const int u   = t + p * 256;
            const int ks8 = u >> 7;
            const int row = u & 127;
            load_lds16(A  + (size_t)(row0 + row) * K + k0 + ks8 * 8,
                       (char*)&As[buf][0] + p * 4096 + wbase);
            load_lds16(Bm + (size_t)(col0 + row) * K + k0 + ks8 * 8,
                       (char*)&Bs[buf][0] + p * 4096 + wbase);
        }
    };

    const int NT = Ksub >> 6;
    stage(kbase, 0);
    __syncthreads();

    int cur = 0;
    for (int kt = 0; kt < NT; ++kt) {
        if (kt + 1 < NT) stage(kbase + ((kt + 1) << 6), cur ^ 1);

        #pragma unroll
        for (int s = 0; s < 2; ++s) {
            bf16x8 af[4], bf[4];
            #pragma unroll
            for (int i = 0; i < 4; ++i)
                af[i] = *reinterpret_cast<const bf16x8*>(
                    &As[cur][(s * 4 + kslot) * (128 * 8) + (wr * 64 + i * 16 + lrow) * 8]);
            #pragma unroll
            for (int j = 0; j < 4; ++j)
                bf[j] = *reinterpret_cast<const bf16x8*>(
                    &Bs[cur][(s * 4 + kslot) * (128 * 8) + (wc * 64 + j * 16 + lrow) * 8]);
            #pragma unroll
            for (int i = 0; i < 4; ++i)
                #pragma unroll
                for (int j = 0; j < 4; ++j)
                    acc[i][j] = __builtin_amdgcn_mfma_f32_16x16x32_bf16(af[i], bf[j], acc[i][j], 0, 0, 0);
        }
        __syncthreads();
        cur ^= 1;
    }

    #pragma unroll
    for (int i = 0; i < 4; ++i) {
        const int r0 = row0 + wr * 64 + i * 16 + (lane >> 4) * 4;
        #pragma unroll
        for (int j = 0; j < 4; ++j) {
            const int c = col0 + wc * 64 + j * 16 + lrow;
            #pragma unroll
            for (int q = 0; q < 4; ++q) {
                const int r = r0 + q;
                C[(size_t)r * N + c] = acc[i][j][q];
            }
        }
    }
}

// ---------------------------------------------------------------------------
// Causal depthwise conv(4) + bias + SiLU -> bf16 xcb.
// ---------------------------------------------------------------------------
__global__ __launch_bounds__(256) void conv_silu(
    const float* __restrict__ xz, const float* __restrict__ Wc,
    const float* __restrict__ bc, unsigned short* __restrict__ xcb)
{
    int idx = blockIdx.x * 256 + threadIdx.x;      // m*DIN + e
    int e = idx & (DIN - 1);
    int m = idx >> 11;
    int l = m & (LSEQ - 1);

    const float4 w = reinterpret_cast<const float4*>(Wc)[e];
    float acc = bc[e];
    if (l >= 3) acc = fmaf(xz[(size_t)(m - 3) * (2 * DIN) + e], w.x, acc);
    if (l >= 2) acc = fmaf(xz[(size_t)(m - 2) * (2 * DIN) + e], w.y, acc);
    if (l >= 1) acc = fmaf(xz[(size_t)(m - 1) * (2 * DIN) + e], w.z, acc);
    acc = fmaf(xz[(size_t)m * (2 * DIN) + e], w.w, acc);
    float s = acc / (1.0f + __expf(-acc));
    xcb[idx] = f2bf(s);
}

// ---------------------------------------------------------------------------
// Chunked selective scan — pass 1. B_t read from BC[m*128 + s] (P layout).
// ---------------------------------------------------------------------------
__global__ __launch_bounds__(256) void scan_pass1(
    const float* __restrict__ delta, const unsigned short* __restrict__ xcb,
    const float* __restrict__ BC, const float* __restrict__ A_log,
    float* __restrict__ hfin, float* __restrict__ dsums)
{
    const int ge = blockIdx.x * 256 + threadIdx.x;
    const int c  = blockIdx.y;
    const int b  = ge >> 11;
    const int e  = ge & (DIN - 1);

    float A[DSTATE];
    #pragma unroll
    for (int s = 0; s < DSTATE; ++s) A[s] = -__expf(A_log[s]);

    float h[DSTATE] = {};
    float dsum = 0.0f;
    const int m0 = b * LSEQ + c * LC;

    for (int l = 0; l < LC; ++l) {
        const int m = m0 + l;
        const float dv = delta[(size_t)m * DIN + e];
        const float xv = bf2f(xcb[(size_t)m * DIN + e]);
        dsum += dv;
        const float dx = dv * xv;
        #pragma unroll
        for (int s = 0; s < DSTATE; ++s) {
            const float bv = BC[(size_t)m * 128 + s];
            h[s] = fmaf(h[s], __expf(dv * A[s]), dx * bv);
        }
    }

    float4* hf = reinterpret_cast<float4*>(&hfin[((size_t)ge * NCHUNK + c) * DSTATE]);
    #pragma unroll
    for (int q = 0; q < 4; ++q)
        hf[q] = make_float4(h[4*q], h[4*q+1], h[4*q+2], h[4*q+3]);
    dsums[(size_t)ge * NCHUNK + c] = dsum;
}

// ---------------------------------------------------------------------------
// Pass 2: sequential combine over chunks (in place).
// ---------------------------------------------------------------------------
__global__ __launch_bounds__(256) void scan_pass2(
    float* __restrict__ hfin, const float* __restrict__ dsums,
    const float* __restrict__ A_log)
{
    const int t  = blockIdx.x * 256 + threadIdx.x;
    const int ge = t >> 4;
    const int s  = t & 15;
    const float A = -__expf(A_log[s]);

    float h = 0.0f;
    for (int c = 0; c < NCHUNK; ++c) {
        const size_t idx = ((size_t)ge * NCHUNK + c) * DSTATE + s;
        const float hf = hfin[idx];
        hfin[idx] = h;
        const float P = __expf(A * dsums[(size_t)ge * NCHUNK + c]);
        h = fmaf(P, h, hf);
    }
}

// ---------------------------------------------------------------------------
// Pass 3: B_t = BC[m*128+s], C_t = BC[m*128+16+s]; fuse D, silu(z); bf16 out.
// ---------------------------------------------------------------------------
__global__ __launch_bounds__(256) void scan_pass3(
    const float* __restrict__ delta, const unsigned short* __restrict__ xcb,
    const float* __restrict__ BC, const float* __restrict__ xz,
    const float* __restrict__ A_log, const float* __restrict__ Dv,
    const float* __restrict__ hcar, unsigned short* __restrict__ ygb)
{
    const int ge = blockIdx.x * 256 + threadIdx.x;
    const int c  = blockIdx.y;
    const int b  = ge >> 11;
    const int e  = ge & (DIN - 1);

    float A[DSTATE];
    #pragma unroll
    for (int s = 0; s < DSTATE; ++s) A[s] = -__expf(A_log[s]);

    float h[DSTATE];
    const float4* hc = reinterpret_cast<const float4*>(&hcar[((size_t)ge * NCHUNK + c) * DSTATE]);
    #pragma unroll
    for (int q = 0; q < 4; ++q) {
        const float4 v = hc[q];
        h[4*q]   = v.x; h[4*q+1] = v.y; h[4*q+2] = v.z; h[4*q+3] = v.w;
    }

    const float Dval = Dv[e];
    const int m0 = b * LSEQ + c * LC;

    for (int l = 0; l < LC; ++l) {
        const int m = m0 + l;
        const float dv = delta[(size_t)m * DIN + e];
        const float xv = bf2f(xcb[(size_t)m * DIN + e]);
        const float dx = dv * xv;
        float y = xv * Dval;
        #pragma unroll
        for (int s = 0; s < DSTATE; ++s) {
            const float bv = BC[(size_t)m * 128 + s];
            const float cv = BC[(size_t)m * 128 + DSTATE + s];
            h[s] = fmaf(h[s], __expf(dv * A[s]), dx * bv);
            y = fmaf(h[s], cv, y);
        }
        const float zv = xz[(size_t)m * (2 * DIN) + DIN + e];
        const float sz = zv / (1.0f + __expf(-zv));
        ygb[(size_t)m * DIN + e] = f2bf(y * sz);
    }
}

// ---------------------------------------------------------------------------
extern "C" void kernel_launch(void* const* d_in, const int* in_sizes, int n_in,
                              void* d_out, int out_size, void* d_ws, size_t ws_size,
                              hipStream_t stream)
{
    const float* x      = (const float*)d_in[0];
    const float* W_in   = (const float*)d_in[1];
    const float* W_conv = (const float*)d_in[2];
    const float* b_conv = (const float*)d_in[3];
    const float* W_dt   = (const float*)d_in[4];
    const float* b_dt   = (const float*)d_in[5];
    const float* W_B    = (const float*)d_in[6];
    const float* W_C    = (const float*)d_in[7];
    const float* A_log  = (const float*)d_in[8];
    const float* Dvec   = (const float*)d_in[9];
    const float* W_out  = (const float*)d_in[10];
    float* out = (float*)d_out;

    // Workspace layout (85.75 MB total):
    float* ws    = (float*)d_ws;
    float* xz    = ws;                                  // [2048,4096] f32  32 MB
    float* delta = xz + (size_t)MROWS * 2 * DIN;        // [2048,2048] f32  16 MB
    float* Bt    = delta + (size_t)MROWS * DIN;         // (unused, keeps offsets)
    float* Ct    = Bt + (size_t)MROWS * DSTATE;
    float* hfin  = Ct + (size_t)MROWS * DSTATE;         // [4096,32,16] f32  8 MB
    float* dsums = hfin + (size_t)CH * NCHUNK * DSTATE; // [4096,32]   f32  0.5 MB
    unsigned short* xb   = (unsigned short*)(dsums + (size_t)CH * NCHUNK); // [2048,1024] bf16 4 MB
    unsigned short* wbuf = xb + (size_t)MROWS * DIM;        // up to 4M bf16   8 MB
    unsigned short* xcb  = wbuf + (size_t)4 * 1024 * 1024;  // [2048,2048] bf16 8 MB
    unsigned short* ygb  = xcb + (size_t)MROWS * DIN;       // [2048,2048] bf16 8 MB
    float* Pbc   = (float*)(ygb + (size_t)MROWS * DIN);     // [2048,128]  f32  1 MB

    // region-reuse views (fp32) for split-K partials
    float* hfinF  = hfin;                                   // 8 MB: G2 P1 rows<1024; later G3 Q2
    float* ygbF   = (float*)ygb;                            // 8 MB: G2 P1 rows>=1024 (pre-offset)
    float* xcbF   = (float*)xcb;                            // 8 MB: G3 Q3
    const size_t SZ3 = (size_t)MROWS * DIM;                 // 2M floats = 8 MB

    // 1. xz = x @ W_in^T   [2048,4096], K=1024 -> 512 blocks (2/CU), plain
    f32_to_bf16<<<(MROWS * DIM) / 1024, 256, 0, stream>>>(x, xb, MROWS * DIM);
    f32_to_bf16<<<(2 * DIN * DIM) / 1024, 256, 0, stream>>>(W_in, wbuf, 2 * DIN * DIM);
    gemm_bf16<0><<<dim3((2 * DIN) / 128, MROWS / 128, 1), 256, 0, stream>>>(
        xb, wbuf, MROWS, 2 * DIN, DIM, DIM, xz, nullptr, nullptr, nullptr);

    // 2. causal conv + silu -> xcb (bf16)
    conv_silu<<<(MROWS * DIN) / 256, 256, 0, stream>>>(xz, W_conv, b_conv, xcb);

    // 3. delta partials: z=2 split (512 blocks, 2/CU), plain stores.
    f32_to_bf16<<<(DIN * DIN) / 1024, 256, 0, stream>>>(W_dt, wbuf, DIN * DIN);
    gemm_bf16<1><<<dim3(DIN / 128, MROWS / 128, 2), 256, 0, stream>>>(
        xcb, wbuf, MROWS, DIN, DIN, DIN / 2,
        delta, hfinF, ygbF - (size_t)1024 * DIN, nullptr);
    finalize_delta<<<(MROWS * DIN) / 1024, 256, 0, stream>>>(
        delta, hfinF, ygbF - (size_t)1024 * DIN, b_dt);

    // 4. B_t/C_t via skinny MFMA GEMM: Pbc = xcb @ [W_B;W_C;0]^T  [2048,128]
    wbc_build<<<(128 * DIN) / 256, 256, 0, stream>>>(W_B, W_C, wbuf);
    gemm_bf16<0><<<dim3(1, MROWS / 128, 1), 256, 0, stream>>>(
        xcb, wbuf, MROWS, 128, DIN, DIN, Pbc, nullptr, nullptr, nullptr);

    // 5. chunked selective scan -> ygb (bf16)
    scan_pass1<<<dim3(CH / 256, NCHUNK), 256, 0, stream>>>(
        delta, xcb, Pbc, A_log, hfin, dsums);
    scan_pass2<<<(CH * DSTATE) / 256, 256, 0, stream>>>(hfin, dsums, A_log);
    scan_pass3<<<dim3(CH / 256, NCHUNK), 256, 0, stream>>>(
        delta, xcb, Pbc, xz, A_log, Dvec, hfin, ygb);

    // 6. out partials: z=4 split (512 blocks, 2/CU), plain stores into
    //    dead regions: Q0,Q1 = delta region; Q2 = hfin; Q3 = xcb region.
    f32_to_bf16<<<(DIM * DIN) / 1024, 256, 0, stream>>>(W_out, wbuf, DIM * DIN);
    gemm_bf16<2><<<dim3(DIM / 128, MROWS / 128, 4), 256, 0, stream>>>(
        ygb, wbuf, MROWS, DIM, DIN, DIN / 4,
        delta, delta + SZ3, hfinF, xcbF);
    out_combine<<<(MROWS * DIM) / 1024, 256, 0, stream>>>(
        x, delta, delta + SZ3, hfinF, xcbF, out);
}

// Round 11
// 248.168 us; speedup vs baseline: 1.2449x; 1.1497x over previous
//
#include <hip/hip_runtime.h>
#include <math.h>

// Problem constants (fixed by the reference)
#define B_SZ    2
#define LSEQ    1024
#define DIM     1024
#define DSTATE  16
#define DCONV   4
#define DIN     2048          // d_inner
#define MROWS   (B_SZ * LSEQ) // 2048
#define CH      (B_SZ * DIN)  // 4096 channels
#define NCHUNK  32
#define LC      (LSEQ / NCHUNK)  // 32

typedef short  bf16x8 __attribute__((ext_vector_type(8)));
typedef float  f32x4  __attribute__((ext_vector_type(4)));

__device__ __forceinline__ float softplus_f(float x) {
    return fmaxf(x, 0.0f) + log1pf(__expf(-fabsf(x)));
}

__device__ __forceinline__ unsigned short f2bf(float x) {
    unsigned u = __float_as_uint(x);
    u = (u + 0x7FFF + ((u >> 16) & 1)) >> 16;
    return (unsigned short)u;
}

__device__ __forceinline__ float bf2f(unsigned short u) {
    return __uint_as_float((unsigned)u << 16);
}

__device__ __forceinline__ void load_lds16(const void* g, void* l) {
    __builtin_amdgcn_global_load_lds(
        (const __attribute__((address_space(1))) unsigned int*)g,
        (__attribute__((address_space(3))) unsigned int*)l, 16, 0, 0);
}

// ---------------------------------------------------------------------------
// f32 -> bf16 conversion (vectorized, 4 elems/thread)
// ---------------------------------------------------------------------------
__global__ __launch_bounds__(256) void f32_to_bf16(
    const float* __restrict__ src, unsigned short* __restrict__ dst, int n)
{
    int i = (blockIdx.x * 256 + threadIdx.x) * 4;
    if (i >= n) return;
    const float4 v = *reinterpret_cast<const float4*>(src + i);
    ushort4 o;
    o.x = f2bf(v.x); o.y = f2bf(v.y); o.z = f2bf(v.z); o.w = f2bf(v.w);
    *reinterpret_cast<ushort4*>(dst + i) = o;
}

// ---------------------------------------------------------------------------
// Pack [W_B; W_C; zero-pad] -> Wbc [128][DIN] bf16 for the skinny MFMA GEMM.
// ---------------------------------------------------------------------------
__global__ __launch_bounds__(256) void wbc_build(
    const float* __restrict__ WB, const float* __restrict__ WC,
    unsigned short* __restrict__ Wbc)
{
    int idx = blockIdx.x * 256 + threadIdx.x;   // row*DIN + j, row in [0,128)
    int row = idx >> 11;
    int j   = idx & (DIN - 1);
    float v = 0.0f;
    if (row < DSTATE)           v = WB[(size_t)row * DIN + j];
    else if (row < 2 * DSTATE)  v = WC[(size_t)(row - DSTATE) * DIN + j];
    Wbc[idx] = f2bf(v);
}

// ---------------------------------------------------------------------------
// Pbc = sum of 8 split-K partial slices [8][MROWS][128] -> [MROWS][128]
// ---------------------------------------------------------------------------
__global__ __launch_bounds__(256) void bc_combine(
    const float* __restrict__ P, float* __restrict__ Pbc)
{
    const size_t STR = (size_t)MROWS * 128;
    int i = (blockIdx.x * 256 + threadIdx.x) * 4;
    float4 a = *reinterpret_cast<const float4*>(P + i);
    #pragma unroll
    for (int s = 1; s < 8; ++s) {
        const float4 q = *reinterpret_cast<const float4*>(P + s * STR + i);
        a.x += q.x; a.y += q.y; a.z += q.z; a.w += q.w;
    }
    *reinterpret_cast<float4*>(Pbc + i) = a;
}

// ---------------------------------------------------------------------------
// delta = softplus(P0 + P1 + b_dt[col]); P1 split across two regions by row.
// ---------------------------------------------------------------------------
__global__ __launch_bounds__(256) void finalize_delta(
    float* __restrict__ delta, const float* __restrict__ P1lo,
    const float* __restrict__ P1hi, const float* __restrict__ b_dt)
{
    int i = (blockIdx.x * 256 + threadIdx.x) * 4;
    int r = i >> 11;
    const float* p1 = (r < 1024) ? P1lo : P1hi;
    float4 v = *reinterpret_cast<float4*>(delta + i);
    const float4 u = *reinterpret_cast<const float4*>(p1 + i);
    const float4 b = *reinterpret_cast<const float4*>(b_dt + (i & (DIN - 1)));
    v.x = softplus_f(v.x + u.x + b.x);
    v.y = softplus_f(v.y + u.y + b.y);
    v.z = softplus_f(v.z + u.z + b.z);
    v.w = softplus_f(v.w + u.w + b.w);
    *reinterpret_cast<float4*>(delta + i) = v;
}

// out = x + Q0 + Q1 + Q2 + Q3   [MROWS*DIM]
__global__ __launch_bounds__(256) void out_combine(
    const float* __restrict__ x, const float* __restrict__ Q0,
    const float* __restrict__ Q1, const float* __restrict__ Q2,
    const float* __restrict__ Q3, float* __restrict__ out)
{
    int i = (blockIdx.x * 256 + threadIdx.x) * 4;
    const float4 a = *reinterpret_cast<const float4*>(x + i);
    const float4 q0 = *reinterpret_cast<const float4*>(Q0 + i);
    const float4 q1 = *reinterpret_cast<const float4*>(Q1 + i);
    const float4 q2 = *reinterpret_cast<const float4*>(Q2 + i);
    const float4 q3 = *reinterpret_cast<const float4*>(Q3 + i);
    float4 o;
    o.x = a.x + ((q0.x + q1.x) + (q2.x + q3.x));
    o.y = a.y + ((q0.y + q1.y) + (q2.y + q3.y));
    o.z = a.z + ((q0.z + q1.z) + (q2.z + q3.z));
    o.w = a.w + ((q0.w + q1.w) + (q2.w + q3.w));
    *reinterpret_cast<float4*>(out + i) = o;
}

// ---------------------------------------------------------------------------
// bf16 MFMA NT GEMM (r8 core): 128x128 tile, BK=64, dbuf LDS 64 KB,
// k-slot-major conflict-free layout, plain-store split-K partials.
//   MODE 0: C0[r*N+c]                       (single slice)
//   MODE 1: z0->C0; z1-> (row<1024 ? C1 : C2)[r*N+c]   (C2 pre-offset)
//   MODE 2: {C0,C1,C2,C3}[z][r*N+c]
//   MODE 3: C0 + z*M*N  (contiguous partial slices)
// ---------------------------------------------------------------------------
template <int MODE>
__global__ __launch_bounds__(256) void gemm_bf16(
    const unsigned short* __restrict__ A, const unsigned short* __restrict__ Bm,
    int M, int N, int K, int Ksub,
    float* __restrict__ C0, float* __restrict__ C1,
    float* __restrict__ C2, float* __restrict__ C3)
{
    __shared__ unsigned short As[2][128 * 64];   // 2 x 16 KB
    __shared__ unsigned short Bs[2][128 * 64];   // 2 x 16 KB

    const int t    = threadIdx.x;
    const int lane = t & 63;
    const int w    = t >> 6;
    const int wr   = w >> 1;
    const int wc   = w & 1;
    const int row0 = blockIdx.y * 128;
    const int col0 = blockIdx.x * 128;
    const int z     = blockIdx.z;
    const int kbase = z * Ksub;

    const int lrow  = lane & 15;
    const int kslot = lane >> 4;

    float* C = C0;
    if (MODE == 1 && z == 1) C = (row0 < 1024) ? C1 : C2;
    if (MODE == 2) C = (z == 0) ? C0 : (z == 1) ? C1 : (z == 2) ? C2 : C3;
    if (MODE == 3) C = C0 + (size_t)z * ((size_t)M * N);

    f32x4 acc[4][4];
    #pragma unroll
    for (int i = 0; i < 4; ++i)
        #pragma unroll
        for (int j = 0; j < 4; ++j)
            acc[i][j] = (f32x4){0.f, 0.f, 0.f, 0.f};

    const int wbase = w << 10;

    auto stage = [&](int k0, int buf) {
        #pragma unroll
        for (int p = 0; p < 4; ++p) {
            const int u   = t + p * 256;
            const int ks8 = u >> 7;
            const int row = u & 127;
            load_lds16(A  + (size_t)(row0 + row) * K + k0 + ks8 * 8,
                       (char*)&As[buf][0] + p * 4096 + wbase);
            load_lds16(Bm + (size_t)(col0 + row) * K + k0 + ks8 * 8,
                       (char*)&Bs[buf][0] + p * 4096 + wbase);
        }
    };

    const int NT = Ksub >> 6;
    stage(kbase, 0);
    __syncthreads();

    int cur = 0;
    for (int kt = 0; kt < NT; ++kt) {
        if (kt + 1 < NT) stage(kbase + ((kt + 1) << 6), cur ^ 1);

        #pragma unroll
        for (int s = 0; s < 2; ++s) {
            bf16x8 af[4], bf[4];
            #pragma unroll
            for (int i = 0; i < 4; ++i)
                af[i] = *reinterpret_cast<const bf16x8*>(
                    &As[cur][(s * 4 + kslot) * (128 * 8) + (wr * 64 + i * 16 + lrow) * 8]);
            #pragma unroll
            for (int j = 0; j < 4; ++j)
                bf[j] = *reinterpret_cast<const bf16x8*>(
                    &Bs[cur][(s * 4 + kslot) * (128 * 8) + (wc * 64 + j * 16 + lrow) * 8]);
            #pragma unroll
            for (int i = 0; i < 4; ++i)
                #pragma unroll
                for (int j = 0; j < 4; ++j)
                    acc[i][j] = __builtin_amdgcn_mfma_f32_16x16x32_bf16(af[i], bf[j], acc[i][j], 0, 0, 0);
        }
        __syncthreads();
        cur ^= 1;
    }

    #pragma unroll
    for (int i = 0; i < 4; ++i) {
        const int r0 = row0 + wr * 64 + i * 16 + (lane >> 4) * 4;
        #pragma unroll
        for (int j = 0; j < 4; ++j) {
            const int c = col0 + wc * 64 + j * 16 + lrow;
            #pragma unroll
            for (int q = 0; q < 4; ++q) {
                const int r = r0 + q;
                C[(size_t)r * N + c] = acc[i][j][q];
            }
        }
    }
}

// ---------------------------------------------------------------------------
// Causal depthwise conv(4) + bias + SiLU -> bf16 xcb.
// ---------------------------------------------------------------------------
__global__ __launch_bounds__(256) void conv_silu(
    const float* __restrict__ xz, const float* __restrict__ Wc,
    const float* __restrict__ bc, unsigned short* __restrict__ xcb)
{
    int idx = blockIdx.x * 256 + threadIdx.x;      // m*DIN + e
    int e = idx & (DIN - 1);
    int m = idx >> 11;
    int l = m & (LSEQ - 1);

    const float4 w = reinterpret_cast<const float4*>(Wc)[e];
    float acc = bc[e];
    if (l >= 3) acc = fmaf(xz[(size_t)(m - 3) * (2 * DIN) + e], w.x, acc);
    if (l >= 2) acc = fmaf(xz[(size_t)(m - 2) * (2 * DIN) + e], w.y, acc);
    if (l >= 1) acc = fmaf(xz[(size_t)(m - 1) * (2 * DIN) + e], w.z, acc);
    acc = fmaf(xz[(size_t)m * (2 * DIN) + e], w.w, acc);
    float s = acc / (1.0f + __expf(-acc));
    xcb[idx] = f2bf(s);
}

// ---------------------------------------------------------------------------
// Chunked selective scan — pass 1. B_t read from BC[m*128 + s] (P layout).
// ---------------------------------------------------------------------------
__global__ __launch_bounds__(256) void scan_pass1(
    const float* __restrict__ delta, const unsigned short* __restrict__ xcb,
    const float* __restrict__ BC, const float* __restrict__ A_log,
    float* __restrict__ hfin, float* __restrict__ dsums)
{
    const int ge = blockIdx.x * 256 + threadIdx.x;
    const int c  = blockIdx.y;
    const int b  = ge >> 11;
    const int e  = ge & (DIN - 1);

    float A[DSTATE];
    #pragma unroll
    for (int s = 0; s < DSTATE; ++s) A[s] = -__expf(A_log[s]);

    float h[DSTATE] = {};
    float dsum = 0.0f;
    const int m0 = b * LSEQ + c * LC;

    for (int l = 0; l < LC; ++l) {
        const int m = m0 + l;
        const float dv = delta[(size_t)m * DIN + e];
        const float xv = bf2f(xcb[(size_t)m * DIN + e]);
        dsum += dv;
        const float dx = dv * xv;
        #pragma unroll
        for (int s = 0; s < DSTATE; ++s) {
            const float bv = BC[(size_t)m * 128 + s];
            h[s] = fmaf(h[s], __expf(dv * A[s]), dx * bv);
        }
    }

    float4* hf = reinterpret_cast<float4*>(&hfin[((size_t)ge * NCHUNK + c) * DSTATE]);
    #pragma unroll
    for (int q = 0; q < 4; ++q)
        hf[q] = make_float4(h[4*q], h[4*q+1], h[4*q+2], h[4*q+3]);
    dsums[(size_t)ge * NCHUNK + c] = dsum;
}

// ---------------------------------------------------------------------------
// Pass 2: sequential combine over chunks (in place).
// ---------------------------------------------------------------------------
__global__ __launch_bounds__(256) void scan_pass2(
    float* __restrict__ hfin, const float* __restrict__ dsums,
    const float* __restrict__ A_log)
{
    const int t  = blockIdx.x * 256 + threadIdx.x;
    const int ge = t >> 4;
    const int s  = t & 15;
    const float A = -__expf(A_log[s]);

    float h = 0.0f;
    for (int c = 0; c < NCHUNK; ++c) {
        const size_t idx = ((size_t)ge * NCHUNK + c) * DSTATE + s;
        const float hf = hfin[idx];
        hfin[idx] = h;
        const float P = __expf(A * dsums[(size_t)ge * NCHUNK + c]);
        h = fmaf(P, h, hf);
    }
}

// ---------------------------------------------------------------------------
// Pass 3: B_t = BC[m*128+s], C_t = BC[m*128+16+s]; fuse D, silu(z); bf16 out.
// ---------------------------------------------------------------------------
__global__ __launch_bounds__(256) void scan_pass3(
    const float* __restrict__ delta, const unsigned short* __restrict__ xcb,
    const float* __restrict__ BC, const float* __restrict__ xz,
    const float* __restrict__ A_log, const float* __restrict__ Dv,
    const float* __restrict__ hcar, unsigned short* __restrict__ ygb)
{
    const int ge = blockIdx.x * 256 + threadIdx.x;
    const int c  = blockIdx.y;
    const int b  = ge >> 11;
    const int e  = ge & (DIN - 1);

    float A[DSTATE];
    #pragma unroll
    for (int s = 0; s < DSTATE; ++s) A[s] = -__expf(A_log[s]);

    float h[DSTATE];
    const float4* hc = reinterpret_cast<const float4*>(&hcar[((size_t)ge * NCHUNK + c) * DSTATE]);
    #pragma unroll
    for (int q = 0; q < 4; ++q) {
        const float4 v = hc[q];
        h[4*q]   = v.x; h[4*q+1] = v.y; h[4*q+2] = v.z; h[4*q+3] = v.w;
    }

    const float Dval = Dv[e];
    const int m0 = b * LSEQ + c * LC;

    for (int l = 0; l < LC; ++l) {
        const int m = m0 + l;
        const float dv = delta[(size_t)m * DIN + e];
        const float xv = bf2f(xcb[(size_t)m * DIN + e]);
        const float dx = dv * xv;
        float y = xv * Dval;
        #pragma unroll
        for (int s = 0; s < DSTATE; ++s) {
            const float bv = BC[(size_t)m * 128 + s];
            const float cv = BC[(size_t)m * 128 + DSTATE + s];
            h[s] = fmaf(h[s], __expf(dv * A[s]), dx * bv);
            y = fmaf(h[s], cv, y);
        }
        const float zv = xz[(size_t)m * (2 * DIN) + DIN + e];
        const float sz = zv / (1.0f + __expf(-zv));
        ygb[(size_t)m * DIN + e] = f2bf(y * sz);
    }
}

// ---------------------------------------------------------------------------
extern "C" void kernel_launch(void* const* d_in, const int* in_sizes, int n_in,
                              void* d_out, int out_size, void* d_ws, size_t ws_size,
                              hipStream_t stream)
{
    const float* x      = (const float*)d_in[0];
    const float* W_in   = (const float*)d_in[1];
    const float* W_conv = (const float*)d_in[2];
    const float* b_conv = (const float*)d_in[3];
    const float* W_dt   = (const float*)d_in[4];
    const float* b_dt   = (const float*)d_in[5];
    const float* W_B    = (const float*)d_in[6];
    const float* W_C    = (const float*)d_in[7];
    const float* A_log  = (const float*)d_in[8];
    const float* Dvec   = (const float*)d_in[9];
    const float* W_out  = (const float*)d_in[10];
    float* out = (float*)d_out;

    // Workspace layout (85.75 MB total):
    float* ws    = (float*)d_ws;
    float* xz    = ws;                                  // [2048,4096] f32  32 MB
    float* delta = xz + (size_t)MROWS * 2 * DIN;        // [2048,2048] f32  16 MB
    float* Bt    = delta + (size_t)MROWS * DIN;         // (unused, keeps offsets)
    float* Ct    = Bt + (size_t)MROWS * DSTATE;
    float* hfin  = Ct + (size_t)MROWS * DSTATE;         // [4096,32,16] f32  8 MB
    float* dsums = hfin + (size_t)CH * NCHUNK * DSTATE; // [4096,32]   f32  0.5 MB
    unsigned short* xb   = (unsigned short*)(dsums + (size_t)CH * NCHUNK); // [2048,1024] bf16 4 MB
    unsigned short* wbuf = xb + (size_t)MROWS * DIM;        // up to 4M bf16   8 MB
    unsigned short* xcb  = wbuf + (size_t)4 * 1024 * 1024;  // [2048,2048] bf16 8 MB
    unsigned short* ygb  = xcb + (size_t)MROWS * DIN;       // [2048,2048] bf16 8 MB
    float* Pbc   = (float*)(ygb + (size_t)MROWS * DIN);     // [2048,128]  f32  1 MB

    // region-reuse views (fp32) for split-K partials
    float* hfinF  = hfin;   // 8 MB: G2 P1 rows<1024; then bc partials [8][2048][128]; then G3 Q2
    float* ygbF   = (float*)ygb;                            // 8 MB: G2 P1 rows>=1024 (pre-offset)
    float* xcbF   = (float*)xcb;                            // 8 MB: G3 Q3
    const size_t SZ3 = (size_t)MROWS * DIM;                 // 2M floats = 8 MB

    // 1. xz = x @ W_in^T   [2048,4096], K=1024 -> 512 blocks (2/CU), plain
    f32_to_bf16<<<(MROWS * DIM) / 1024, 256, 0, stream>>>(x, xb, MROWS * DIM);
    f32_to_bf16<<<(2 * DIN * DIM) / 1024, 256, 0, stream>>>(W_in, wbuf, 2 * DIN * DIM);
    gemm_bf16<0><<<dim3((2 * DIN) / 128, MROWS / 128, 1), 256, 0, stream>>>(
        xb, wbuf, MROWS, 2 * DIN, DIM, DIM, xz, nullptr, nullptr, nullptr);

    // 2. causal conv + silu -> xcb (bf16)
    conv_silu<<<(MROWS * DIN) / 256, 256, 0, stream>>>(xz, W_conv, b_conv, xcb);

    // 3. delta partials: z=2 split (512 blocks, 2/CU), plain stores.
    f32_to_bf16<<<(DIN * DIN) / 1024, 256, 0, stream>>>(W_dt, wbuf, DIN * DIN);
    gemm_bf16<1><<<dim3(DIN / 128, MROWS / 128, 2), 256, 0, stream>>>(
        xcb, wbuf, MROWS, DIN, DIN, DIN / 2,
        delta, hfinF, ygbF - (size_t)1024 * DIN, nullptr);
    finalize_delta<<<(MROWS * DIN) / 1024, 256, 0, stream>>>(
        delta, hfinF, ygbF - (size_t)1024 * DIN, b_dt);

    // 4. B_t/C_t via skinny MFMA GEMM, K split 8-way -> 128 blocks.
    //    Partials into hfin region (dead: finalize_delta already consumed it).
    wbc_build<<<(128 * DIN) / 256, 256, 0, stream>>>(W_B, W_C, wbuf);
    gemm_bf16<3><<<dim3(1, MROWS / 128, 8), 256, 0, stream>>>(
        xcb, wbuf, MROWS, 128, DIN, DIN / 8, hfinF, nullptr, nullptr, nullptr);
    bc_combine<<<(MROWS * 128) / 1024, 256, 0, stream>>>(hfinF, Pbc);

    // 5. chunked selective scan -> ygb (bf16; scan_pass1 overwrites hfin)
    scan_pass1<<<dim3(CH / 256, NCHUNK), 256, 0, stream>>>(
        delta, xcb, Pbc, A_log, hfin, dsums);
    scan_pass2<<<(CH * DSTATE) / 256, 256, 0, stream>>>(hfin, dsums, A_log);
    scan_pass3<<<dim3(CH / 256, NCHUNK), 256, 0, stream>>>(
        delta, xcb, Pbc, xz, A_log, Dvec, hfin, ygb);

    // 6. out partials: z=4 split (512 blocks, 2/CU), plain stores into
    //    dead regions: Q0,Q1 = delta region; Q2 = hfin; Q3 = xcb region.
    f32_to_bf16<<<(DIM * DIN) / 1024, 256, 0, stream>>>(W_out, wbuf, DIM * DIN);
    gemm_bf16<2><<<dim3(DIM / 128, MROWS / 128, 4), 256, 0, stream>>>(
        ygb, wbuf, MROWS, DIM, DIN, DIN / 4,
        delta, delta + SZ3, hfinF, xcbF);
    out_combine<<<(MROWS * DIM) / 1024, 256, 0, stream>>>(
        x, delta, delta + SZ3, hfinF, xcbF, out);
}

// Round 13
// 238.110 us; speedup vs baseline: 1.2975x; 1.0422x over previous
//
#include <hip/hip_runtime.h>
#include <math.h>

// Problem constants (fixed by the reference)
#define B_SZ    2
#define LSEQ    1024
#define DIM     1024
#define DSTATE  16
#define DCONV   4
#define DIN     2048          // d_inner
#define MROWS   (B_SZ * LSEQ) // 2048
#define CH      (B_SZ * DIN)  // 4096 channels
#define NCHUNK  32
#define LC      (LSEQ / NCHUNK)  // 32

typedef short  bf16x8 __attribute__((ext_vector_type(8)));
typedef float  f32x4  __attribute__((ext_vector_type(4)));

__device__ __forceinline__ float softplus_f(float x) {
    return fmaxf(x, 0.0f) + log1pf(__expf(-fabsf(x)));
}

__device__ __forceinline__ unsigned short f2bf(float x) {
    unsigned u = __float_as_uint(x);
    u = (u + 0x7FFF + ((u >> 16) & 1)) >> 16;
    return (unsigned short)u;
}

__device__ __forceinline__ float bf2f(unsigned short u) {
    return __uint_as_float((unsigned)u << 16);
}

__device__ __forceinline__ void load_lds16(const void* g, void* l) {
    __builtin_amdgcn_global_load_lds(
        (const __attribute__((address_space(1))) unsigned int*)g,
        (__attribute__((address_space(3))) unsigned int*)l, 16, 0, 0);
}

__device__ __forceinline__ void cvt4(const float* __restrict__ s,
                                     unsigned short* __restrict__ d, int i) {
    const float4 v = *reinterpret_cast<const float4*>(s + i);
    ushort4 o;
    o.x = f2bf(v.x); o.y = f2bf(v.y); o.z = f2bf(v.z); o.w = f2bf(v.w);
    *reinterpret_cast<ushort4*>(d + i) = o;
}

// ---------------------------------------------------------------------------
// Fused converts: blocks [0,2048) convert x (2M elems);
// blocks [2048,6144) convert W_in (4M elems = 2*DIN*DIM).
// ---------------------------------------------------------------------------
__global__ __launch_bounds__(256) void convert_x_win(
    const float* __restrict__ x, const float* __restrict__ W_in,
    unsigned short* __restrict__ xb, unsigned short* __restrict__ wbuf)
{
    int blk = blockIdx.x;
    if (blk < 2048) {
        cvt4(x, xb, (blk * 256 + threadIdx.x) * 4);
    } else {
        cvt4(W_in, wbuf, ((blk - 2048) * 256 + threadIdx.x) * 4);
    }
}

// blocks [0,4096): W_dt (4M elems) -> wbuf ; [4096,5120): pack Wbc (256K elems)
__global__ __launch_bounds__(256) void convert_wdt_wbc(
    const float* __restrict__ W_dt, const float* __restrict__ WB,
    const float* __restrict__ WC, unsigned short* __restrict__ wbuf,
    unsigned short* __restrict__ wbcB)
{
    int blk = blockIdx.x;
    if (blk < 4096) {
        cvt4(W_dt, wbuf, (blk * 256 + threadIdx.x) * 4);
    } else {
        int idx = (blk - 4096) * 256 + threadIdx.x;   // row*DIN + j, row<128
        int row = idx >> 11;
        int j   = idx & (DIN - 1);
        float v = 0.0f;
        if (row < DSTATE)           v = WB[(size_t)row * DIN + j];
        else if (row < 2 * DSTATE)  v = WC[(size_t)(row - DSTATE) * DIN + j];
        wbcB[idx] = f2bf(v);
    }
}

// blocks [0,4096): delta = softplus(P0+P1+b_dt) (4M elems, in place on P0);
// blocks [4096,6144): W_out (2M elems) -> wbuf
__global__ __launch_bounds__(256) void finalize_wout(
    float* __restrict__ delta, const float* __restrict__ P1lo,
    const float* __restrict__ P1hi, const float* __restrict__ b_dt,
    const float* __restrict__ W_out, unsigned short* __restrict__ wbuf)
{
    int blk = blockIdx.x;
    if (blk < 4096) {
        int i = (blk * 256 + threadIdx.x) * 4;
        int r = i >> 11;
        const float* p1 = (r < 1024) ? P1lo : P1hi;
        float4 v = *reinterpret_cast<float4*>(delta + i);
        const float4 u = *reinterpret_cast<const float4*>(p1 + i);
        const float4 b = *reinterpret_cast<const float4*>(b_dt + (i & (DIN - 1)));
        v.x = softplus_f(v.x + u.x + b.x);
        v.y = softplus_f(v.y + u.y + b.y);
        v.z = softplus_f(v.z + u.z + b.z);
        v.w = softplus_f(v.w + u.w + b.w);
        *reinterpret_cast<float4*>(delta + i) = v;
    } else {
        cvt4(W_out, wbuf, ((blk - 4096) * 256 + threadIdx.x) * 4);
    }
}

// ---------------------------------------------------------------------------
// Pbc = sum of 8 split-K partial slices [8][MROWS][128] -> [MROWS][128]
// ---------------------------------------------------------------------------
__global__ __launch_bounds__(256) void bc_combine(
    const float* __restrict__ P, float* __restrict__ Pbc)
{
    const size_t STR = (size_t)MROWS * 128;
    int i = (blockIdx.x * 256 + threadIdx.x) * 4;
    float4 a = *reinterpret_cast<const float4*>(P + i);
    #pragma unroll
    for (int s = 1; s < 8; ++s) {
        const float4 q = *reinterpret_cast<const float4*>(P + s * STR + i);
        a.x += q.x; a.y += q.y; a.z += q.z; a.w += q.w;
    }
    *reinterpret_cast<float4*>(Pbc + i) = a;
}

// out = x + Q0 + Q1 + Q2 + Q3   [MROWS*DIM]
__global__ __launch_bounds__(256) void out_combine(
    const float* __restrict__ x, const float* __restrict__ Q0,
    const float* __restrict__ Q1, const float* __restrict__ Q2,
    const float* __restrict__ Q3, float* __restrict__ out)
{
    int i = (blockIdx.x * 256 + threadIdx.x) * 4;
    const float4 a = *reinterpret_cast<const float4*>(x + i);
    const float4 q0 = *reinterpret_cast<const float4*>(Q0 + i);
    const float4 q1 = *reinterpret_cast<const float4*>(Q1 + i);
    const float4 q2 = *reinterpret_cast<const float4*>(Q2 + i);
    const float4 q3 = *reinterpret_cast<const float4*>(Q3 + i);
    float4 o;
    o.x = a.x + ((q0.x + q1.x) + (q2.x + q3.x));
    o.y = a.y + ((q0.y + q1.y) + (q2.y + q3.y));
    o.z = a.z + ((q0.z + q1.z) + (q2.z + q3.z));
    o.w = a.w + ((q0.w + q1.w) + (q2.w + q3.w));
    *reinterpret_cast<float4*>(out + i) = o;
}

// ---------------------------------------------------------------------------
// bf16 MFMA NT GEMM (r8 core): 128x128 tile, BK=64, dbuf LDS 64 KB,
// k-slot-major conflict-free layout, plain-store split-K partials.
//   MODE 0: f32 C0[r*N+c]                   (single slice)
//   MODE 1: z0->C0; z1-> (row<1024 ? C1 : C2)[r*N+c]   (C2 pre-offset)
//   MODE 2: {C0,C1,C2,C3}[z][r*N+c]
//   MODE 3: C0 + z*M*N  (contiguous partial slices)
//   MODE 4: bf16 out: ((ushort*)C0)[r*N+c] = f2bf(acc)
// ---------------------------------------------------------------------------
template <int MODE>
__global__ __launch_bounds__(256) void gemm_bf16(
    const unsigned short* __restrict__ A, const unsigned short* __restrict__ Bm,
    int M, int N, int K, int Ksub,
    float* __restrict__ C0, float* __restrict__ C1,
    float* __restrict__ C2, float* __restrict__ C3)
{
    __shared__ unsigned short As[2][128 * 64];   // 2 x 16 KB
    __shared__ unsigned short Bs[2][128 * 64];   // 2 x 16 KB

    const int t    = threadIdx.x;
    const int lane = t & 63;
    const int w    = t >> 6;
    const int wr   = w >> 1;
    const int wc   = w & 1;
    const int row0 = blockIdx.y * 128;
    const int col0 = blockIdx.x * 128;
    const int z     = blockIdx.z;
    const int kbase = z * Ksub;

    const int lrow  = lane & 15;
    const int kslot = lane >> 4;

    float* C = C0;
    if (MODE == 1 && z == 1) C = (row0 < 1024) ? C1 : C2;
    if (MODE == 2) C = (z == 0) ? C0 : (z == 1) ? C1 : (z == 2) ? C2 : C3;
    if (MODE == 3) C = C0 + (size_t)z * ((size_t)M * N);

    f32x4 acc[4][4];
    #pragma unroll
    for (int i = 0; i < 4; ++i)
        #pragma unroll
        for (int j = 0; j < 4; ++j)
            acc[i][j] = (f32x4){0.f, 0.f, 0.f, 0.f};

    const int wbase = w << 10;

    auto stage = [&](int k0, int buf) {
        #pragma unroll
        for (int p = 0; p < 4; ++p) {
            const int u   = t + p * 256;
            const int ks8 = u >> 7;
            const int row = u & 127;
            load_lds16(A  + (size_t)(row0 + row) * K + k0 + ks8 * 8,
                       (char*)&As[buf][0] + p * 4096 + wbase);
            load_lds16(Bm + (size_t)(col0 + row) * K + k0 + ks8 * 8,
                       (char*)&Bs[buf][0] + p * 4096 + wbase);
        }
    };

    const int NT = Ksub >> 6;
    stage(kbase, 0);
    __syncthreads();

    int cur = 0;
    for (int kt = 0; kt < NT; ++kt) {
        if (kt + 1 < NT) stage(kbase + ((kt + 1) << 6), cur ^ 1);

        #pragma unroll
        for (int s = 0; s < 2; ++s) {
            bf16x8 af[4], bf[4];
            #pragma unroll
            for (int i = 0; i < 4; ++i)
                af[i] = *reinterpret_cast<const bf16x8*>(
                    &As[cur][(s * 4 + kslot) * (128 * 8) + (wr * 64 + i * 16 + lrow) * 8]);
            #pragma unroll
            for (int j = 0; j < 4; ++j)
                bf[j] = *reinterpret_cast<const bf16x8*>(
                    &Bs[cur][(s * 4 + kslot) * (128 * 8) + (wc * 64 + j * 16 + lrow) * 8]);
            #pragma unroll
            for (int i = 0; i < 4; ++i)
                #pragma unroll
                for (int j = 0; j < 4; ++j)
                    acc[i][j] = __builtin_amdgcn_mfma_f32_16x16x32_bf16(af[i], bf[j], acc[i][j], 0, 0, 0);
        }
        __syncthreads();
        cur ^= 1;
    }

    #pragma unroll
    for (int i = 0; i < 4; ++i) {
        const int r0 = row0 + wr * 64 + i * 16 + (lane >> 4) * 4;
        #pragma unroll
        for (int j = 0; j < 4; ++j) {
            const int c = col0 + wc * 64 + j * 16 + lrow;
            #pragma unroll
            for (int q = 0; q < 4; ++q) {
                const int r = r0 + q;
                if constexpr (MODE == 4) {
                    ((unsigned short*)C0)[(size_t)r * N + c] = f2bf(acc[i][j][q]);
                } else {
                    C[(size_t)r * N + c] = acc[i][j][q];
                }
            }
        }
    }
}

// ---------------------------------------------------------------------------
// Causal depthwise conv(4) + bias + SiLU; reads bf16 xzb -> bf16 xcb.
// ---------------------------------------------------------------------------
__global__ __launch_bounds__(256) void conv_silu(
    const unsigned short* __restrict__ xzb, const float* __restrict__ Wc,
    const float* __restrict__ bc, unsigned short* __restrict__ xcb)
{
    int idx = blockIdx.x * 256 + threadIdx.x;      // m*DIN + e
    int e = idx & (DIN - 1);
    int m = idx >> 11;
    int l = m & (LSEQ - 1);

    const float4 w = reinterpret_cast<const float4*>(Wc)[e];
    float acc = bc[e];
    if (l >= 3) acc = fmaf(bf2f(xzb[(size_t)(m - 3) * (2 * DIN) + e]), w.x, acc);
    if (l >= 2) acc = fmaf(bf2f(xzb[(size_t)(m - 2) * (2 * DIN) + e]), w.y, acc);
    if (l >= 1) acc = fmaf(bf2f(xzb[(size_t)(m - 1) * (2 * DIN) + e]), w.z, acc);
    acc = fmaf(bf2f(xzb[(size_t)m * (2 * DIN) + e]), w.w, acc);
    float s = acc / (1.0f + __expf(-acc));
    xcb[idx] = f2bf(s);
}

// ---------------------------------------------------------------------------
// Chunked selective scan — pass 1. B_t read from BC[m*128 + s] (P layout).
// ---------------------------------------------------------------------------
__global__ __launch_bounds__(256) void scan_pass1(
    const float* __restrict__ delta, const unsigned short* __restrict__ xcb,
    const float* __restrict__ BC, const float* __restrict__ A_log,
    float* __restrict__ hfin, float* __restrict__ dsums)
{
    const int ge = blockIdx.x * 256 + threadIdx.x;
    const int c  = blockIdx.y;
    const int b  = ge >> 11;
    const int e  = ge & (DIN - 1);

    float A[DSTATE];
    #pragma unroll
    for (int s = 0; s < DSTATE; ++s) A[s] = -__expf(A_log[s]);

    float h[DSTATE] = {};
    float dsum = 0.0f;
    const int m0 = b * LSEQ + c * LC;

    for (int l = 0; l < LC; ++l) {
        const int m = m0 + l;
        const float dv = delta[(size_t)m * DIN + e];
        const float xv = bf2f(xcb[(size_t)m * DIN + e]);
        dsum += dv;
        const float dx = dv * xv;
        #pragma unroll
        for (int s = 0; s < DSTATE; ++s) {
            const float bv = BC[(size_t)m * 128 + s];
            h[s] = fmaf(h[s], __expf(dv * A[s]), dx * bv);
        }
    }

    float4* hf = reinterpret_cast<float4*>(&hfin[((size_t)ge * NCHUNK + c) * DSTATE]);
    #pragma unroll
    for (int q = 0; q < 4; ++q)
        hf[q] = make_float4(h[4*q], h[4*q+1], h[4*q+2], h[4*q+3]);
    dsums[(size_t)ge * NCHUNK + c] = dsum;
}

// ---------------------------------------------------------------------------
// Pass 2: sequential combine over chunks (in place).
// ---------------------------------------------------------------------------
__global__ __launch_bounds__(256) void scan_pass2(
    float* __restrict__ hfin, const float* __restrict__ dsums,
    const float* __restrict__ A_log)
{
    const int t  = blockIdx.x * 256 + threadIdx.x;
    const int ge = t >> 4;
    const int s  = t & 15;
    const float A = -__expf(A_log[s]);

    float h = 0.0f;
    for (int c = 0; c < NCHUNK; ++c) {
        const size_t idx = ((size_t)ge * NCHUNK + c) * DSTATE + s;
        const float hf = hfin[idx];
        hfin[idx] = h;
        const float P = __expf(A * dsums[(size_t)ge * NCHUNK + c]);
        h = fmaf(P, h, hf);
    }
}

// ---------------------------------------------------------------------------
// Pass 3: carry-in local scan; C-dot, D, silu(z) from bf16 xzb; bf16 out.
// ---------------------------------------------------------------------------
__global__ __launch_bounds__(256) void scan_pass3(
    const float* __restrict__ delta, const unsigned short* __restrict__ xcb,
    const float* __restrict__ BC, const unsigned short* __restrict__ xzb,
    const float* __restrict__ A_log, const float* __restrict__ Dv,
    const float* __restrict__ hcar, unsigned short* __restrict__ ygb)
{
    const int ge = blockIdx.x * 256 + threadIdx.x;
    const int c  = blockIdx.y;
    const int b  = ge >> 11;
    const int e  = ge & (DIN - 1);

    float A[DSTATE];
    #pragma unroll
    for (int s = 0; s < DSTATE; ++s) A[s] = -__expf(A_log[s]);

    float h[DSTATE];
    const float4* hc = reinterpret_cast<const float4*>(&hcar[((size_t)ge * NCHUNK + c) * DSTATE]);
    #pragma unroll
    for (int q = 0; q < 4; ++q) {
        const float4 v = hc[q];
        h[4*q]   = v.x; h[4*q+1] = v.y; h[4*q+2] = v.z; h[4*q+3] = v.w;
    }

    const float Dval = Dv[e];
    const int m0 = b * LSEQ + c * LC;

    for (int l = 0; l < LC; ++l) {
        const int m = m0 + l;
        const float dv = delta[(size_t)m * DIN + e];
        const float xv = bf2f(xcb[(size_t)m * DIN + e]);
        const float dx = dv * xv;
        float y = xv * Dval;
        #pragma unroll
        for (int s = 0; s < DSTATE; ++s) {
            const float bv = BC[(size_t)m * 128 + s];
            const float cv = BC[(size_t)m * 128 + DSTATE + s];
            h[s] = fmaf(h[s], __expf(dv * A[s]), dx * bv);
            y = fmaf(h[s], cv, y);
        }
        const float zv = bf2f(xzb[(size_t)m * (2 * DIN) + DIN + e]);
        const float sz = zv / (1.0f + __expf(-zv));
        ygb[(size_t)m * DIN + e] = f2bf(y * sz);
    }
}

// ---------------------------------------------------------------------------
extern "C" void kernel_launch(void* const* d_in, const int* in_sizes, int n_in,
                              void* d_out, int out_size, void* d_ws, size_t ws_size,
                              hipStream_t stream)
{
    const float* x      = (const float*)d_in[0];
    const float* W_in   = (const float*)d_in[1];
    const float* W_conv = (const float*)d_in[2];
    const float* b_conv = (const float*)d_in[3];
    const float* W_dt   = (const float*)d_in[4];
    const float* b_dt   = (const float*)d_in[5];
    const float* W_B    = (const float*)d_in[6];
    const float* W_C    = (const float*)d_in[7];
    const float* A_log  = (const float*)d_in[8];
    const float* Dvec   = (const float*)d_in[9];
    const float* W_out  = (const float*)d_in[10];
    float* out = (float*)d_out;

    // Workspace layout (85.75 MB total, offsets unchanged from r11):
    float* ws    = (float*)d_ws;
    float* xz    = ws;                                  // region holds bf16 xzb [2048,4096]
    float* delta = xz + (size_t)MROWS * 2 * DIN;        // [2048,2048] f32  16 MB
    float* Bt    = delta + (size_t)MROWS * DIN;         // (unused, keeps offsets)
    float* Ct    = Bt + (size_t)MROWS * DSTATE;
    float* hfin  = Ct + (size_t)MROWS * DSTATE;         // [4096,32,16] f32  8 MB
    float* dsums = hfin + (size_t)CH * NCHUNK * DSTATE; // [4096,32]   f32  0.5 MB
    unsigned short* xb   = (unsigned short*)(dsums + (size_t)CH * NCHUNK); // 4 MB: x bf16, then Wbc
    unsigned short* wbuf = xb + (size_t)MROWS * DIM;        // 8 MB: W_in / W_dt / W_out bf16
    unsigned short* xcb  = wbuf + (size_t)4 * 1024 * 1024;  // [2048,2048] bf16 8 MB
    unsigned short* ygb  = xcb + (size_t)MROWS * DIN;       // [2048,2048] bf16 8 MB
    float* Pbc   = (float*)(ygb + (size_t)MROWS * DIN);     // [2048,128]  f32  1 MB

    unsigned short* xzb = (unsigned short*)xz;              // bf16 view of xz region
    float* hfinF  = hfin;   // 8 MB: G2 P1lo; then bc partials [8][2048][128]; then G3 Q2
    float* ygbF   = (float*)ygb;                            // 8 MB: G2 P1hi (pre-offset)
    float* xcbF   = (float*)xcb;                            // 8 MB: G3 Q3
    unsigned short* wbcB = xb;                              // 0.5 MB: packed [W_B;W_C;0] (xb dead after G1)
    const size_t SZ3 = (size_t)MROWS * DIM;                 // 2M floats = 8 MB

    // 1. converts (x -> xb: 2048 blocks; W_in -> wbuf: 4096 blocks); G1 bf16 out
    convert_x_win<<<6144, 256, 0, stream>>>(x, W_in, xb, wbuf);
    gemm_bf16<4><<<dim3((2 * DIN) / 128, MROWS / 128, 1), 256, 0, stream>>>(
        xb, wbuf, MROWS, 2 * DIN, DIM, DIM, (float*)xzb, nullptr, nullptr, nullptr);

    // 2. causal conv + silu -> xcb (bf16)
    conv_silu<<<(MROWS * DIN) / 256, 256, 0, stream>>>(xzb, W_conv, b_conv, xcb);

    // 3. W_dt convert (4096 blocks) + Wbc pack (1024 blocks); G2 z=2 partials
    convert_wdt_wbc<<<5120, 256, 0, stream>>>(W_dt, W_B, W_C, wbuf, wbcB);
    gemm_bf16<1><<<dim3(DIN / 128, MROWS / 128, 2), 256, 0, stream>>>(
        xcb, wbuf, MROWS, DIN, DIN, DIN / 2,
        delta, hfinF, ygbF - (size_t)1024 * DIN, nullptr);

    // 4. finalize delta + W_out convert (one dispatch; both depend only on G2)
    finalize_wout<<<6144, 256, 0, stream>>>(
        delta, hfinF, ygbF - (size_t)1024 * DIN, b_dt, W_out, wbuf);

    // 5. B_t/C_t skinny MFMA GEMM, K split 8-way (partials -> hfin, now dead)
    gemm_bf16<3><<<dim3(1, MROWS / 128, 8), 256, 0, stream>>>(
        xcb, wbcB, MROWS, 128, DIN, DIN / 8, hfinF, nullptr, nullptr, nullptr);
    bc_combine<<<(MROWS * 128) / 1024, 256, 0, stream>>>(hfinF, Pbc);

    // 6. chunked selective scan -> ygb (bf16)
    scan_pass1<<<dim3(CH / 256, NCHUNK), 256, 0, stream>>>(
        delta, xcb, Pbc, A_log, hfin, dsums);
    scan_pass2<<<(CH * DSTATE) / 256, 256, 0, stream>>>(hfin, dsums, A_log);
    scan_pass3<<<dim3(CH / 256, NCHUNK), 256, 0, stream>>>(
        delta, xcb, Pbc, xzb, A_log, Dvec, hfin, ygb);

    // 7. out partials: z=4 split, plain stores into dead regions; combine.
    gemm_bf16<2><<<dim3(DIM / 128, MROWS / 128, 4), 256, 0, stream>>>(
        ygb, wbuf, MROWS, DIM, DIN, DIN / 4,
        delta, delta + SZ3, hfinF, xcbF);
    out_combine<<<(MROWS * DIM) / 1024, 256, 0, stream>>>(
        x, delta, delta + SZ3, hfinF, xcbF, out);
}